// Round 11
// baseline (133.965 us; speedup 1.0000x reference)
//
#include <hip/hip_runtime.h>
#include <hip/hip_cooperative_groups.h>
#include <hip/hip_bf16.h>
#include <stdint.h>

namespace cg = cooperative_groups;

#define HS 4096
#define NE 64

using half8 = __attribute__((ext_vector_type(8))) _Float16;
using f32x4 = __attribute__((ext_vector_type(4))) float;

constexpr int KSPLIT = 8;
constexpr int KPS    = HS / KSPLIT;     // 512 k per split
constexpr int M_BLK  = 256;             // tokens per block (8 waves x 32)

constexpr float XS  = 16.f;             // x scale (keeps xl out of f16 denormals)
constexpr float WSC = 1024.f;           // W scale (keeps Wl out of f16 denormals)
constexpr float INV_SCALE = 1.f / (XS * WSC);   // 2^-14

// Single cooperative kernel: split-f16 MFMA GEMM (K split across blockIdx.y)
// -> partials in ws -> grid.sync -> distributed softmax/top-2 finish.
// W LDS layout swizzled: phys = row*64 + (col ^ ((row>>1)&7));  row = kgl*2+plane.
__global__ __launch_bounds__(512, 1)
void router_all(const float* __restrict__ x, const float* __restrict__ W,
                float* __restrict__ ws, float* __restrict__ out, int n_tokens)
{
    __shared__ half8 Wl8[128 * NE];      // 128 KiB

    const int tid = threadIdx.x;
    const int l   = tid & 63;
    const int wv  = __builtin_amdgcn_readfirstlane(tid >> 6);
    const int g   = l >> 4;              // k-group 0..3
    const int e   = l & 15;              // row/col within 16x16 tile
    const int k0  = blockIdx.y * KPS;

    // ---- W staging: all 16 global loads issued up front (static names) ----
    const int se = tid >> 3;             // expert row 0..63
    const int sc = tid & 7;              // k-group column 0..7
    const float* wrow = W + (size_t)se * HS + k0 + sc * 8;

    float4 u0 = *(const float4*)(wrow +   0), v0 = *(const float4*)(wrow +   4);
    float4 u1 = *(const float4*)(wrow +  64), v1 = *(const float4*)(wrow +  68);
    float4 u2 = *(const float4*)(wrow + 128), v2 = *(const float4*)(wrow + 132);
    float4 u3 = *(const float4*)(wrow + 192), v3 = *(const float4*)(wrow + 196);
    float4 u4 = *(const float4*)(wrow + 256), v4 = *(const float4*)(wrow + 260);
    float4 u5 = *(const float4*)(wrow + 320), v5 = *(const float4*)(wrow + 324);
    float4 u6 = *(const float4*)(wrow + 384), v6 = *(const float4*)(wrow + 388);
    float4 u7 = *(const float4*)(wrow + 448), v7 = *(const float4*)(wrow + 452);

    auto cvt_store = [&](float4 u, float4 v, int kgl) {
        float f[8] = {u.x, u.y, u.z, u.w, v.x, v.y, v.z, v.w};
        half8 h, lo;
        #pragma unroll
        for (int i = 0; i < 8; ++i) {
            float s = f[i] * WSC;
            _Float16 hh = (_Float16)s;
            h[i] = hh; lo[i] = (_Float16)(s - (float)hh);
        }
        const int base = (kgl * 2) * NE + (se ^ (kgl & 7));   // swizzled col
        Wl8[base]      = h;          // hi plane, row kgl*2
        Wl8[base + NE] = lo;         // lo plane, row kgl*2+1 (same col swizzle)
    };

    // ---- x pipeline (depth 2), rows for this wave's two M-tiles ----
    const int m0 = blockIdx.x * M_BLK + wv * 32;
    const float* xr0 = x + (size_t)(m0 + e) * HS + k0 + g * 8;
    const float* xr1 = xr0 + (size_t)16 * HS;

    f32x4 acc[2][4];
    #pragma unroll
    for (int i = 0; i < 2; ++i)
        #pragma unroll
        for (int j = 0; j < 4; ++j) acc[i][j] = (f32x4){0.f, 0.f, 0.f, 0.f};

    float4 a00 = *(const float4*)(xr0),      a01 = *(const float4*)(xr0 + 4);
    float4 a10 = *(const float4*)(xr1),      a11 = *(const float4*)(xr1 + 4);
    float4 b00 = *(const float4*)(xr0 + 32), b01 = *(const float4*)(xr0 + 36);
    float4 b10 = *(const float4*)(xr1 + 32), b11 = *(const float4*)(xr1 + 36);

    // ---- two staging phases, each followed by 8 k-steps ----
    #pragma unroll 1
    for (int half = 0; half < 2; ++half) {
        if (half == 0) {
            cvt_store(u0, v0, sc);       cvt_store(u1, v1, sc + 8);
            cvt_store(u2, v2, sc + 16);  cvt_store(u3, v3, sc + 24);
        } else {
            // disjoint LDS rows (64..127) -> no WAR vs phase-0 readers
            cvt_store(u4, v4, sc + 32);  cvt_store(u5, v5, sc + 40);
            cvt_store(u6, v6, sc + 48);  cvt_store(u7, v7, sc + 56);
        }
        __syncthreads();

        #pragma unroll 2
        for (int ks = half * 8; ks < half * 8 + 8; ++ks) {
            float4 d00 = b00, d01 = b01, d10 = b10, d11 = b11;
            if (ks + 2 < 16) {
                const float* p0 = xr0 + (ks + 2) * 32;
                const float* p1 = xr1 + (ks + 2) * 32;
                d00 = *(const float4*)(p0); d01 = *(const float4*)(p0 + 4);
                d10 = *(const float4*)(p1); d11 = *(const float4*)(p1 + 4);
            }

            // B fragments (hi/lo planes), swizzled reads
            const int kgl = ks * 4 + g;
            const int rb  = kgl * 2;
            const int sw  = kgl & 7;
            half8 bh0 = Wl8[(rb + 0) * NE + (( 0 + e) ^ sw)];
            half8 bl0 = Wl8[(rb + 1) * NE + (( 0 + e) ^ sw)];
            half8 bh1 = Wl8[(rb + 0) * NE + ((16 + e) ^ sw)];
            half8 bl1 = Wl8[(rb + 1) * NE + ((16 + e) ^ sw)];
            half8 bh2 = Wl8[(rb + 0) * NE + ((32 + e) ^ sw)];
            half8 bl2 = Wl8[(rb + 1) * NE + ((32 + e) ^ sw)];
            half8 bh3 = Wl8[(rb + 0) * NE + ((48 + e) ^ sw)];
            half8 bl3 = Wl8[(rb + 1) * NE + ((48 + e) ^ sw)];

            // A fragments: fp32 -> scaled f16 hi/lo
            half8 ah0, al0, ah1, al1;
            {
                float f0[8] = {a00.x, a00.y, a00.z, a00.w, a01.x, a01.y, a01.z, a01.w};
                float f1[8] = {a10.x, a10.y, a10.z, a10.w, a11.x, a11.y, a11.z, a11.w};
                #pragma unroll
                for (int i = 0; i < 8; ++i) {
                    float s0 = f0[i] * XS; _Float16 h0 = (_Float16)s0;
                    ah0[i] = h0; al0[i] = (_Float16)(s0 - (float)h0);
                    float s1 = f1[i] * XS; _Float16 h1 = (_Float16)s1;
                    ah1[i] = h1; al1[i] = (_Float16)(s1 - (float)h1);
                }
            }

            // 3-term split-f16 accumulation: xh*Wh + xl*Wh + xh*Wl
            acc[0][0] = __builtin_amdgcn_mfma_f32_16x16x32_f16(ah0, bh0, acc[0][0], 0, 0, 0);
            acc[0][0] = __builtin_amdgcn_mfma_f32_16x16x32_f16(al0, bh0, acc[0][0], 0, 0, 0);
            acc[0][0] = __builtin_amdgcn_mfma_f32_16x16x32_f16(ah0, bl0, acc[0][0], 0, 0, 0);
            acc[0][1] = __builtin_amdgcn_mfma_f32_16x16x32_f16(ah0, bh1, acc[0][1], 0, 0, 0);
            acc[0][1] = __builtin_amdgcn_mfma_f32_16x16x32_f16(al0, bh1, acc[0][1], 0, 0, 0);
            acc[0][1] = __builtin_amdgcn_mfma_f32_16x16x32_f16(ah0, bl1, acc[0][1], 0, 0, 0);
            acc[0][2] = __builtin_amdgcn_mfma_f32_16x16x32_f16(ah0, bh2, acc[0][2], 0, 0, 0);
            acc[0][2] = __builtin_amdgcn_mfma_f32_16x16x32_f16(al0, bh2, acc[0][2], 0, 0, 0);
            acc[0][2] = __builtin_amdgcn_mfma_f32_16x16x32_f16(ah0, bl2, acc[0][2], 0, 0, 0);
            acc[0][3] = __builtin_amdgcn_mfma_f32_16x16x32_f16(ah0, bh3, acc[0][3], 0, 0, 0);
            acc[0][3] = __builtin_amdgcn_mfma_f32_16x16x32_f16(al0, bh3, acc[0][3], 0, 0, 0);
            acc[0][3] = __builtin_amdgcn_mfma_f32_16x16x32_f16(ah0, bl3, acc[0][3], 0, 0, 0);
            acc[1][0] = __builtin_amdgcn_mfma_f32_16x16x32_f16(ah1, bh0, acc[1][0], 0, 0, 0);
            acc[1][0] = __builtin_amdgcn_mfma_f32_16x16x32_f16(al1, bh0, acc[1][0], 0, 0, 0);
            acc[1][0] = __builtin_amdgcn_mfma_f32_16x16x32_f16(ah1, bl0, acc[1][0], 0, 0, 0);
            acc[1][1] = __builtin_amdgcn_mfma_f32_16x16x32_f16(ah1, bh1, acc[1][1], 0, 0, 0);
            acc[1][1] = __builtin_amdgcn_mfma_f32_16x16x32_f16(al1, bh1, acc[1][1], 0, 0, 0);
            acc[1][1] = __builtin_amdgcn_mfma_f32_16x16x32_f16(ah1, bl1, acc[1][1], 0, 0, 0);
            acc[1][2] = __builtin_amdgcn_mfma_f32_16x16x32_f16(ah1, bh2, acc[1][2], 0, 0, 0);
            acc[1][2] = __builtin_amdgcn_mfma_f32_16x16x32_f16(al1, bh2, acc[1][2], 0, 0, 0);
            acc[1][2] = __builtin_amdgcn_mfma_f32_16x16x32_f16(ah1, bl2, acc[1][2], 0, 0, 0);
            acc[1][3] = __builtin_amdgcn_mfma_f32_16x16x32_f16(ah1, bh3, acc[1][3], 0, 0, 0);
            acc[1][3] = __builtin_amdgcn_mfma_f32_16x16x32_f16(al1, bh3, acc[1][3], 0, 0, 0);
            acc[1][3] = __builtin_amdgcn_mfma_f32_16x16x32_f16(ah1, bl3, acc[1][3], 0, 0, 0);

            a00 = b00; a01 = b01; a10 = b10; a11 = b11;
            b00 = d00; b01 = d01; b10 = d10; b11 = d11;
        }
    }

    // ---- partials: C layout col=lane&15 (expert), row=(lane>>4)*4+reg (token) ----
    #pragma unroll
    for (int mt = 0; mt < 2; ++mt)
        #pragma unroll
        for (int nt = 0; nt < 4; ++nt)
            #pragma unroll
            for (int r = 0; r < 4; ++r) {
                const int tok = m0 + mt * 16 + g * 4 + r;
                const int ex  = nt * 16 + e;
                ws[((size_t)blockIdx.y * n_tokens + tok) * NE + ex] = acc[mt][nt][r];
            }

    __threadfence();
    cg::this_grid().sync();

    // ---- finish: each block owns 32 tokens; one wave per 4 tokens ----
    const int tb = blockIdx.y * gridDim.x + blockIdx.x;   // 0..255
    #pragma unroll 1
    for (int jj = 0; jj < 4; ++jj) {
        const int token = tb * 32 + wv * 4 + jj;
        if (token >= n_tokens) break;

        float v = 0.f;
        #pragma unroll
        for (int s = 0; s < KSPLIT; ++s)
            v += ws[((size_t)s * n_tokens + token) * NE + l];
        v *= INV_SCALE;

        float m1 = v;
        #pragma unroll
        for (int off = 32; off >= 1; off >>= 1) m1 = fmaxf(m1, __shfl_xor(m1, off));
        unsigned long long b1 = __ballot(v == m1);        // lowest-index tie-break
        int i1 = __ffsll(b1) - 1;

        const float NINF = __int_as_float(0xff800000);
        float vx = (l == i1) ? NINF : v;
        float m2 = vx;
        #pragma unroll
        for (int off = 32; off >= 1; off >>= 1) m2 = fmaxf(m2, __shfl_xor(m2, off));
        unsigned long long b2 = __ballot(vx == m2);
        int i2 = __ffsll(b2) - 1;

        float s = __expf(v - m1);
        #pragma unroll
        for (int off = 32; off >= 1; off >>= 1) s += __shfl_xor(s, off);

        if (l == 0) {
            float inv = 1.0f / s;
            out[(size_t)token * 2 + 0] = inv;
            out[(size_t)token * 2 + 1] = __expf(m2 - m1) * inv;
            out[(size_t)n_tokens * 2 + (size_t)token * 2 + 0] = (float)i1;
            out[(size_t)n_tokens * 2 + (size_t)token * 2 + 1] = (float)i2;
        }
    }
}

extern "C" void kernel_launch(void* const* d_in, const int* in_sizes, int n_in,
                              void* d_out, int out_size, void* d_ws, size_t ws_size,
                              hipStream_t stream)
{
    const float* x = (const float*)d_in[0];
    const float* W = (const float*)d_in[1];
    float* out = (float*)d_out;
    float* ws  = (float*)d_ws;

    int n_tokens = in_sizes[0] / HS;                  // 8192
    dim3 grid(n_tokens / M_BLK, KSPLIT);              // (32, 8) = 256 blocks, 1/CU

    void* args[] = {(void*)&x, (void*)&W, (void*)&ws, (void*)&out, (void*)&n_tokens};
    hipLaunchCooperativeKernel((void*)router_all, grid, dim3(512), args, 0, stream);
}

// Round 12
// 35.858 us; speedup vs baseline: 3.7360x; 3.7360x over previous
//
#include <hip/hip_runtime.h>
#include <hip/hip_bf16.h>
#include <stdint.h>

#define HS 4096
#define NE 64

using half8 = __attribute__((ext_vector_type(8))) _Float16;
using f32x4 = __attribute__((ext_vector_type(4))) float;

constexpr int KSPLIT = 8;
constexpr int KPS    = HS / KSPLIT;     // 512 k per split
constexpr int M_BLK  = 256;             // tokens per block (8 waves x 32)

constexpr float XS  = 16.f;             // x scale (keeps xl out of f16 denormals)
constexpr float WSC = 1024.f;           // W scale (keeps Wl out of f16 denormals)
constexpr float INV_SCALE = 1.f / (XS * WSC);   // 2^-14

// GEMM: split-f16 MFMA, K split across blockIdx.y. Two-phase swizzled W
// staging (R11-proven): all 16 global loads up front, phase-1 convert/store
// overlaps phase-0 compute. W LDS: row = kgl*2+plane, col = se ^ (kgl&7).
__global__ __launch_bounds__(512, 1)
void router_gemm(const float* __restrict__ x, const float* __restrict__ W,
                 float* __restrict__ ws, int n_tokens)
{
    __shared__ half8 Wl8[128 * NE];      // 128 KiB

    const int tid = threadIdx.x;
    const int l   = tid & 63;
    const int wv  = __builtin_amdgcn_readfirstlane(tid >> 6);
    const int g   = l >> 4;              // k-group 0..3
    const int e   = l & 15;              // row/col within 16x16 tile
    const int k0  = blockIdx.y * KPS;

    // ---- W staging: all 16 global loads issued up front (static names) ----
    const int se = tid >> 3;             // expert row 0..63
    const int sc = tid & 7;              // k-group column 0..7
    const float* wrow = W + (size_t)se * HS + k0 + sc * 8;

    float4 u0 = *(const float4*)(wrow +   0), v0 = *(const float4*)(wrow +   4);
    float4 u1 = *(const float4*)(wrow +  64), v1 = *(const float4*)(wrow +  68);
    float4 u2 = *(const float4*)(wrow + 128), v2 = *(const float4*)(wrow + 132);
    float4 u3 = *(const float4*)(wrow + 192), v3 = *(const float4*)(wrow + 196);
    float4 u4 = *(const float4*)(wrow + 256), v4 = *(const float4*)(wrow + 260);
    float4 u5 = *(const float4*)(wrow + 320), v5 = *(const float4*)(wrow + 324);
    float4 u6 = *(const float4*)(wrow + 384), v6 = *(const float4*)(wrow + 388);
    float4 u7 = *(const float4*)(wrow + 448), v7 = *(const float4*)(wrow + 452);

    auto cvt_store = [&](float4 u, float4 v, int kgl) {
        float f[8] = {u.x, u.y, u.z, u.w, v.x, v.y, v.z, v.w};
        half8 h, lo;
        #pragma unroll
        for (int i = 0; i < 8; ++i) {
            float s = f[i] * WSC;
            _Float16 hh = (_Float16)s;
            h[i] = hh; lo[i] = (_Float16)(s - (float)hh);
        }
        const int base = (kgl * 2) * NE + (se ^ (kgl & 7));   // swizzled col
        Wl8[base]      = h;          // hi plane
        Wl8[base + NE] = lo;         // lo plane (same col swizzle)
    };

    // ---- x pipeline (depth 2), rows for this wave's two M-tiles ----
    const int m0 = blockIdx.x * M_BLK + wv * 32;
    const float* xr0 = x + (size_t)(m0 + e) * HS + k0 + g * 8;
    const float* xr1 = xr0 + (size_t)16 * HS;

    f32x4 acc[2][4];
    #pragma unroll
    for (int i = 0; i < 2; ++i)
        #pragma unroll
        for (int j = 0; j < 4; ++j) acc[i][j] = (f32x4){0.f, 0.f, 0.f, 0.f};

    float4 a00 = *(const float4*)(xr0),      a01 = *(const float4*)(xr0 + 4);
    float4 a10 = *(const float4*)(xr1),      a11 = *(const float4*)(xr1 + 4);
    float4 b00 = *(const float4*)(xr0 + 32), b01 = *(const float4*)(xr0 + 36);
    float4 b10 = *(const float4*)(xr1 + 32), b11 = *(const float4*)(xr1 + 36);

    // ---- two staging phases, each followed by 8 k-steps ----
    #pragma unroll 1
    for (int half = 0; half < 2; ++half) {
        if (half == 0) {
            cvt_store(u0, v0, sc);       cvt_store(u1, v1, sc + 8);
            cvt_store(u2, v2, sc + 16);  cvt_store(u3, v3, sc + 24);
        } else {
            // disjoint LDS rows (64..127) -> no WAR vs phase-0 readers
            cvt_store(u4, v4, sc + 32);  cvt_store(u5, v5, sc + 40);
            cvt_store(u6, v6, sc + 48);  cvt_store(u7, v7, sc + 56);
        }
        __syncthreads();

        #pragma unroll 2
        for (int ks = half * 8; ks < half * 8 + 8; ++ks) {
            float4 d00 = b00, d01 = b01, d10 = b10, d11 = b11;
            if (ks + 2 < 16) {
                const float* p0 = xr0 + (ks + 2) * 32;
                const float* p1 = xr1 + (ks + 2) * 32;
                d00 = *(const float4*)(p0); d01 = *(const float4*)(p0 + 4);
                d10 = *(const float4*)(p1); d11 = *(const float4*)(p1 + 4);
            }

            // B fragments (hi/lo planes), swizzled reads
            const int kgl = ks * 4 + g;
            const int rb  = kgl * 2;
            const int sw  = kgl & 7;
            half8 bh0 = Wl8[(rb + 0) * NE + (( 0 + e) ^ sw)];
            half8 bl0 = Wl8[(rb + 1) * NE + (( 0 + e) ^ sw)];
            half8 bh1 = Wl8[(rb + 0) * NE + ((16 + e) ^ sw)];
            half8 bl1 = Wl8[(rb + 1) * NE + ((16 + e) ^ sw)];
            half8 bh2 = Wl8[(rb + 0) * NE + ((32 + e) ^ sw)];
            half8 bl2 = Wl8[(rb + 1) * NE + ((32 + e) ^ sw)];
            half8 bh3 = Wl8[(rb + 0) * NE + ((48 + e) ^ sw)];
            half8 bl3 = Wl8[(rb + 1) * NE + ((48 + e) ^ sw)];

            // A fragments: fp32 -> scaled f16 hi/lo
            half8 ah0, al0, ah1, al1;
            {
                float f0[8] = {a00.x, a00.y, a00.z, a00.w, a01.x, a01.y, a01.z, a01.w};
                float f1[8] = {a10.x, a10.y, a10.z, a10.w, a11.x, a11.y, a11.z, a11.w};
                #pragma unroll
                for (int i = 0; i < 8; ++i) {
                    float s0 = f0[i] * XS; _Float16 h0 = (_Float16)s0;
                    ah0[i] = h0; al0[i] = (_Float16)(s0 - (float)h0);
                    float s1 = f1[i] * XS; _Float16 h1 = (_Float16)s1;
                    ah1[i] = h1; al1[i] = (_Float16)(s1 - (float)h1);
                }
            }

            // 3-term split-f16 accumulation: xh*Wh + xl*Wh + xh*Wl
            acc[0][0] = __builtin_amdgcn_mfma_f32_16x16x32_f16(ah0, bh0, acc[0][0], 0, 0, 0);
            acc[0][0] = __builtin_amdgcn_mfma_f32_16x16x32_f16(al0, bh0, acc[0][0], 0, 0, 0);
            acc[0][0] = __builtin_amdgcn_mfma_f32_16x16x32_f16(ah0, bl0, acc[0][0], 0, 0, 0);
            acc[0][1] = __builtin_amdgcn_mfma_f32_16x16x32_f16(ah0, bh1, acc[0][1], 0, 0, 0);
            acc[0][1] = __builtin_amdgcn_mfma_f32_16x16x32_f16(al0, bh1, acc[0][1], 0, 0, 0);
            acc[0][1] = __builtin_amdgcn_mfma_f32_16x16x32_f16(ah0, bl1, acc[0][1], 0, 0, 0);
            acc[0][2] = __builtin_amdgcn_mfma_f32_16x16x32_f16(ah0, bh2, acc[0][2], 0, 0, 0);
            acc[0][2] = __builtin_amdgcn_mfma_f32_16x16x32_f16(al0, bh2, acc[0][2], 0, 0, 0);
            acc[0][2] = __builtin_amdgcn_mfma_f32_16x16x32_f16(ah0, bl2, acc[0][2], 0, 0, 0);
            acc[0][3] = __builtin_amdgcn_mfma_f32_16x16x32_f16(ah0, bh3, acc[0][3], 0, 0, 0);
            acc[0][3] = __builtin_amdgcn_mfma_f32_16x16x32_f16(al0, bh3, acc[0][3], 0, 0, 0);
            acc[0][3] = __builtin_amdgcn_mfma_f32_16x16x32_f16(ah0, bl3, acc[0][3], 0, 0, 0);
            acc[1][0] = __builtin_amdgcn_mfma_f32_16x16x32_f16(ah1, bh0, acc[1][0], 0, 0, 0);
            acc[1][0] = __builtin_amdgcn_mfma_f32_16x16x32_f16(al1, bh0, acc[1][0], 0, 0, 0);
            acc[1][0] = __builtin_amdgcn_mfma_f32_16x16x32_f16(ah1, bl0, acc[1][0], 0, 0, 0);
            acc[1][1] = __builtin_amdgcn_mfma_f32_16x16x32_f16(ah1, bh1, acc[1][1], 0, 0, 0);
            acc[1][1] = __builtin_amdgcn_mfma_f32_16x16x32_f16(al1, bh1, acc[1][1], 0, 0, 0);
            acc[1][1] = __builtin_amdgcn_mfma_f32_16x16x32_f16(ah1, bl1, acc[1][1], 0, 0, 0);
            acc[1][2] = __builtin_amdgcn_mfma_f32_16x16x32_f16(ah1, bh2, acc[1][2], 0, 0, 0);
            acc[1][2] = __builtin_amdgcn_mfma_f32_16x16x32_f16(al1, bh2, acc[1][2], 0, 0, 0);
            acc[1][2] = __builtin_amdgcn_mfma_f32_16x16x32_f16(ah1, bl2, acc[1][2], 0, 0, 0);
            acc[1][3] = __builtin_amdgcn_mfma_f32_16x16x32_f16(ah1, bh3, acc[1][3], 0, 0, 0);
            acc[1][3] = __builtin_amdgcn_mfma_f32_16x16x32_f16(al1, bh3, acc[1][3], 0, 0, 0);
            acc[1][3] = __builtin_amdgcn_mfma_f32_16x16x32_f16(ah1, bl3, acc[1][3], 0, 0, 0);

            a00 = b00; a01 = b01; a10 = b10; a11 = b11;
            b00 = d00; b01 = d01; b10 = d10; b11 = d11;
        }
    }

    // ---- partials: C layout col=lane&15 (expert), row=(lane>>4)*4+reg (token) ----
    #pragma unroll
    for (int mt = 0; mt < 2; ++mt)
        #pragma unroll
        for (int nt = 0; nt < 4; ++nt)
            #pragma unroll
            for (int r = 0; r < 4; ++r) {
                const int tok = m0 + mt * 16 + g * 4 + r;
                const int ex  = nt * 16 + e;
                ws[((size_t)blockIdx.y * n_tokens + tok) * NE + ex] = acc[mt][nt][r];
            }
}

// Finish: reduce k-splits, unscale, softmax, top-2. One wave per token.
__global__ __launch_bounds__(256)
void router_finish(const float* __restrict__ ws, float* __restrict__ out,
                   int n_tokens)
{
    const int lane  = threadIdx.x & 63;
    const int token = blockIdx.x * 4 + (threadIdx.x >> 6);
    if (token >= n_tokens) return;

    float v = 0.f;
    #pragma unroll
    for (int s = 0; s < KSPLIT; ++s)
        v += ws[((size_t)s * n_tokens + token) * NE + lane];
    v *= INV_SCALE;                                   // undo 2^14 input scaling

    float m1 = v;
    #pragma unroll
    for (int off = 32; off >= 1; off >>= 1) m1 = fmaxf(m1, __shfl_xor(m1, off));
    unsigned long long b1 = __ballot(v == m1);        // lowest-index tie-break
    int i1 = __ffsll(b1) - 1;

    const float NINF = __int_as_float(0xff800000);
    float vx = (lane == i1) ? NINF : v;
    float m2 = vx;
    #pragma unroll
    for (int off = 32; off >= 1; off >>= 1) m2 = fmaxf(m2, __shfl_xor(m2, off));
    unsigned long long b2 = __ballot(vx == m2);
    int i2 = __ffsll(b2) - 1;

    float s = __expf(v - m1);
    #pragma unroll
    for (int off = 32; off >= 1; off >>= 1) s += __shfl_xor(s, off);

    if (lane == 0) {
        float inv = 1.0f / s;
        out[(size_t)token * 2 + 0] = inv;
        out[(size_t)token * 2 + 1] = __expf(m2 - m1) * inv;
        out[(size_t)n_tokens * 2 + (size_t)token * 2 + 0] = (float)i1;
        out[(size_t)n_tokens * 2 + (size_t)token * 2 + 1] = (float)i2;
    }
}

extern "C" void kernel_launch(void* const* d_in, const int* in_sizes, int n_in,
                              void* d_out, int out_size, void* d_ws, size_t ws_size,
                              hipStream_t stream)
{
    const float* x = (const float*)d_in[0];
    const float* W = (const float*)d_in[1];
    float* out = (float*)d_out;
    float* ws  = (float*)d_ws;

    const int n_tokens = in_sizes[0] / HS;            // 8192

    dim3 grid1(n_tokens / M_BLK, KSPLIT);             // (32, 8) = 256 blocks, 1/CU
    router_gemm<<<grid1, 512, 0, stream>>>(x, W, ws, n_tokens);

    dim3 grid2((n_tokens + 3) / 4);
    router_finish<<<grid2, 256, 0, stream>>>(ws, out, n_tokens);
}